// Round 1
// baseline (158.010 us; speedup 1.0000x reference)
//
#include <hip/hip_runtime.h>

#define LLEN 65536
#define CIN 64
#define COUT 64
#define TL 256

// ---------------------------------------------------------------------------
// Pack kernel: binarize weights into (wpos, nz) 64-bit word pairs per (co,k),
// and precompute fused epilogue constants A[co] = scale*Ntot + bias,
// S[co] = -2*scale, plus nnz per (co,k) for the edge path.
// ws layout: [0,3072): wbits (192 pairs of u64); [3072,3584): epi A[64],S[64];
//            [3584,4352): nnz[192] ints.
// ---------------------------------------------------------------------------
__global__ void pack_weights(const float* __restrict__ w,
                             const float* __restrict__ wscale,
                             const float* __restrict__ bias,
                             unsigned long long* __restrict__ wbits,
                             float* __restrict__ epi,
                             int* __restrict__ nnz_arr) {
    int co = threadIdx.x;
    if (co >= COUT) return;
    int ntot = 0;
    for (int k = 0; k < 3; ++k) {
        unsigned long long pos = 0ull, nz = 0ull;
        for (int ci = 0; ci < CIN; ++ci) {
            float wv = w[co * (CIN * 3) + ci * 3 + k];
            pos |= ((unsigned long long)(wv > 0.0f)) << ci;
            nz  |= ((unsigned long long)(wv != 0.0f)) << ci;
        }
        wbits[(co * 3 + k) * 2 + 0] = pos;
        wbits[(co * 3 + k) * 2 + 1] = nz;
        int n = __popcll(nz);
        nnz_arr[co * 3 + k] = n;
        ntot += n;
    }
    float s = wscale[co];
    epi[co]        = s * (float)ntot + bias[co];  // A
    epi[COUT + co] = -2.0f * s;                   // S
}

// ---------------------------------------------------------------------------
// Main kernel: one block = (batch b, 256 consecutive l positions).
// Phase 1: each thread packs the 64-channel sign bits for one l into a u64
//          (per-ci loads are coalesced: lanes cover consecutive l).
// Phase 2: each thread computes all 64 co outputs for its l via 3 popcounts,
//          fused scale+bias+RPReLU epilogue, coalesced stores along l.
// ---------------------------------------------------------------------------
__global__ void __launch_bounds__(256) bconv_kernel(
        const float* __restrict__ x,
        const float* __restrict__ alpha,
        const unsigned long long* __restrict__ wbits,
        const float* __restrict__ epi,
        const int* __restrict__ nnz_arr,
        const float* __restrict__ wscale,
        const float* __restrict__ bias,
        const float* __restrict__ beta,
        const float* __restrict__ gamma,
        const float* __restrict__ zeta,
        float* __restrict__ out) {
    __shared__ unsigned long long xw[TL + 2];
    __shared__ unsigned long long wl[COUT * 6];   // [co][k][pos,nz]
    __shared__ float eA[COUT], eS[COUT], eB[COUT], eG[COUT], eZ[COUT];

    const int t = threadIdx.x;
    const int b = blockIdx.y;
    const int lbase = blockIdx.x * TL;

    // stage weight words + epilogue params (used after the barrier)
    for (int i = t; i < COUT * 6; i += 256) wl[i] = wbits[i];
    if (t < COUT) {
        eA[t] = epi[t];
        eS[t] = epi[COUT + t];
        eB[t] = beta[t];
        eG[t] = gamma[t];
        eZ[t] = zeta[t];
    }

    // Phase 1: pack x sign bits. Thread i builds the word for l = lbase-1+i.
    const float* xb_ptr = x + (size_t)b * CIN * LLEN;
    for (int i = t; i < TL + 2; i += 256) {
        int l = lbase - 1 + i;
        unsigned long long word = 0ull;
        if (l >= 0 && l < LLEN) {
            #pragma unroll 8
            for (int ci = 0; ci < CIN; ++ci) {
                float xv = xb_ptr[(size_t)ci * LLEN + l];
                word |= ((unsigned long long)(xv >= alpha[ci])) << ci;
            }
        }
        xw[i] = word;
    }
    __syncthreads();

    // Phase 2: compute outputs for l = lbase + t, all co.
    const unsigned long long xm = xw[t];
    const unsigned long long xc = xw[t + 1];
    const unsigned long long xp = xw[t + 2];
    const int l = lbase + t;
    float* outp = out + (size_t)b * COUT * LLEN + l;

    const bool interior = (l > 0) && (l < LLEN - 1);
    if (interior) {
        #pragma unroll 4
        for (int co = 0; co < COUT; ++co) {
            unsigned long long p0 = wl[co * 6 + 0], n0 = wl[co * 6 + 1];
            unsigned long long p1 = wl[co * 6 + 2], n1 = wl[co * 6 + 3];
            unsigned long long p2 = wl[co * 6 + 4], n2 = wl[co * 6 + 5];
            int pc = __popcll((xm ^ p0) & n0)
                   + __popcll((xc ^ p1) & n1)
                   + __popcll((xp ^ p2) & n2);
            float y  = fmaf(eS[co], (float)pc, eA[co]);
            float xs = y - eG[co];
            float r  = (y > eG[co]) ? (xs + eZ[co]) : fmaf(eB[co], xs, eZ[co]);
            outp[(size_t)co * LLEN] = r;
        }
    } else {
        // edge lanes: zero padding contributes 0 (drop the whole k-term)
        for (int co = 0; co < COUT; ++co) {
            unsigned long long p0 = wl[co * 6 + 0], n0 = wl[co * 6 + 1];
            unsigned long long p1 = wl[co * 6 + 2], n1 = wl[co * 6 + 3];
            unsigned long long p2 = wl[co * 6 + 4], n2 = wl[co * 6 + 5];
            int dot = nnz_arr[co * 3 + 1] - 2 * __popcll((xc ^ p1) & n1);
            if (l - 1 >= 0)
                dot += nnz_arr[co * 3 + 0] - 2 * __popcll((xm ^ p0) & n0);
            if (l + 1 < LLEN)
                dot += nnz_arr[co * 3 + 2] - 2 * __popcll((xp ^ p2) & n2);
            float y  = fmaf(wscale[co], (float)dot, bias[co]);
            float xs = y - eG[co];
            float r  = (y > eG[co]) ? (xs + eZ[co]) : fmaf(eB[co], xs, eZ[co]);
            outp[(size_t)co * LLEN] = r;
        }
    }
}

extern "C" void kernel_launch(void* const* d_in, const int* in_sizes, int n_in,
                              void* d_out, int out_size, void* d_ws, size_t ws_size,
                              hipStream_t stream) {
    const float* x      = (const float*)d_in[0];
    const float* alpha  = (const float*)d_in[1];
    const float* w      = (const float*)d_in[2];
    const float* wscale = (const float*)d_in[3];
    const float* bias   = (const float*)d_in[4];
    const float* beta   = (const float*)d_in[5];
    const float* gamma  = (const float*)d_in[6];
    const float* zeta   = (const float*)d_in[7];
    float* out = (float*)d_out;

    unsigned long long* wbits = (unsigned long long*)d_ws;
    float* epi = (float*)((char*)d_ws + 3072);
    int* nnz   = (int*)((char*)d_ws + 3072 + 512);

    pack_weights<<<1, 64, 0, stream>>>(w, wscale, bias, wbits, epi, nnz);

    dim3 grid(LLEN / TL, 16);
    bconv_kernel<<<grid, 256, 0, stream>>>(x, alpha, wbits, epi, nnz,
                                           wscale, bias, beta, gamma, zeta, out);
}

// Round 2
// 115.620 us; speedup vs baseline: 1.3666x; 1.3666x over previous
//
#include <hip/hip_runtime.h>

#define LLEN 65536
#define CIN 64
#define COUT 64
#define LTILE 1024   // l positions per block (256 threads x 4)

typedef float f32x4 __attribute__((ext_vector_type(4)));

// ---------------------------------------------------------------------------
// Pack kernel: binarize weights into (wpos, nz) u64 pairs per (co,k), plus
// fused epilogue constants A[co] = scale*Ntot + bias, S[co] = -2*scale and
// per-(co,k) nnz for the padding-edge path.
// ws layout: [0,3072) wbits (192 u64 pairs); [3072,3584) epi A[64],S[64];
//            [3584,4352) nnz[192] ints.
// ---------------------------------------------------------------------------
__global__ void pack_weights(const float* __restrict__ w,
                             const float* __restrict__ wscale,
                             const float* __restrict__ bias,
                             unsigned long long* __restrict__ wbits,
                             float* __restrict__ epi,
                             int* __restrict__ nnz_arr) {
    int co = threadIdx.x;
    if (co >= COUT) return;
    int ntot = 0;
    for (int k = 0; k < 3; ++k) {
        unsigned long long pos = 0ull, nz = 0ull;
        for (int ci = 0; ci < CIN; ++ci) {
            float wv = w[co * (CIN * 3) + ci * 3 + k];
            pos |= ((unsigned long long)(wv > 0.0f)) << ci;
            nz  |= ((unsigned long long)(wv != 0.0f)) << ci;
        }
        wbits[(co * 3 + k) * 2 + 0] = pos;
        wbits[(co * 3 + k) * 2 + 1] = nz;
        int n = __popcll(nz);
        nnz_arr[co * 3 + k] = n;
        ntot += n;
    }
    float s = wscale[co];
    epi[co]        = s * (float)ntot + bias[co];  // A
    epi[COUT + co] = -2.0f * s;                   // S
}

__device__ __forceinline__ float rprelu(float y, float B, float G, float Z) {
    float xs = y - G;
    return (y > G) ? (xs + Z) : fmaf(B, xs, Z);
}

// ---------------------------------------------------------------------------
// Main kernel: block = (batch b, 1024 consecutive l). Thread owns 4 l.
// Phase 1: float4 x loads -> 4 packed sign words -> LDS; halo words via
//          one __ballot per edge (lane == ci, wave == 64 == Cin).
// Phase 2: hoist 6 window words to registers; per co read 3 broadcast-LDS
//          b128 weight pairs, 12 popcounts -> float4 epilogue -> nt store.
// ---------------------------------------------------------------------------
__global__ void __launch_bounds__(256) bconv_kernel(
        const float* __restrict__ x,
        const float* __restrict__ alpha,
        const unsigned long long* __restrict__ wbits,
        const float* __restrict__ epi,
        const int* __restrict__ nnz_arr,
        const float* __restrict__ beta,
        const float* __restrict__ gamma,
        const float* __restrict__ zeta,
        float* __restrict__ out) {
    __shared__ unsigned long long xw[LTILE + 2];   // xw[i] = word for l = lbase+i-1
    __shared__ unsigned long long wl[COUT * 6];    // [co][k][pos,nz]
    __shared__ float af[CIN];
    __shared__ float eA[COUT], eS[COUT], eB[COUT], eG[COUT], eZ[COUT];
    __shared__ float h0[COUT], h2[COUT];           // 0.5*nnz(k=0), 0.5*nnz(k=2)

    const int t = threadIdx.x;
    const int b = blockIdx.y;
    const int lbase = blockIdx.x * LTILE;

    if (t < CIN) af[t] = alpha[t];
    for (int i = t; i < COUT * 6; i += 256) wl[i] = wbits[i];
    if (t < COUT) {
        eA[t] = epi[t];
        eS[t] = epi[COUT + t];
        eB[t] = beta[t];
        eG[t] = gamma[t];
        eZ[t] = zeta[t];
        h0[t] = 0.5f * (float)nnz_arr[t * 3 + 0];
        h2[t] = 0.5f * (float)nnz_arr[t * 3 + 2];
    }
    __syncthreads();   // af ready for phase 1

    // Phase 1: pack. Thread t covers l = lbase+4t .. +3 -> xw[4t+1 .. 4t+4]
    const float* xb = x + (size_t)b * CIN * LLEN + lbase + 4 * t;
    unsigned long long w0 = 0, w1 = 0, w2 = 0, w3 = 0;
    #pragma unroll 16
    for (int ci = 0; ci < CIN; ++ci) {
        const f32x4 v = *(const f32x4*)(xb + (size_t)ci * LLEN);
        const float a = af[ci];
        w0 |= ((unsigned long long)(v.x >= a)) << ci;
        w1 |= ((unsigned long long)(v.y >= a)) << ci;
        w2 |= ((unsigned long long)(v.z >= a)) << ci;
        w3 |= ((unsigned long long)(v.w >= a)) << ci;
    }
    xw[4 * t + 1] = w0;
    xw[4 * t + 2] = w1;
    xw[4 * t + 3] = w2;
    xw[4 * t + 4] = w3;

    // Halo words: wave 0 -> l = lbase-1, wave 1 -> l = lbase+LTILE.
    if (t < 64) {
        int l = lbase - 1;
        float v = (l >= 0) ? x[(size_t)b * CIN * LLEN + (size_t)t * LLEN + l] : 0.0f;
        unsigned long long word = __ballot(v >= af[t]);
        if (t == 0) xw[0] = word;                  // garbage if l<0; fixed up below
    } else if (t < 128) {
        int ci = t - 64;
        int l = lbase + LTILE;
        float v = (l < LLEN) ? x[(size_t)b * CIN * LLEN + (size_t)ci * LLEN + l] : 0.0f;
        unsigned long long word = __ballot(v >= af[ci]);
        if (ci == 0) xw[LTILE + 1] = word;         // garbage if l>=LLEN; fixed below
    }
    __syncthreads();

    // Phase 2
    const unsigned long long xq0 = xw[4 * t + 0], xq1 = xw[4 * t + 1],
                             xq2 = xw[4 * t + 2], xq3 = xw[4 * t + 3],
                             xq4 = xw[4 * t + 4], xq5 = xw[4 * t + 5];
    const bool fixlo = (blockIdx.x == 0) && (t == 0);              // l==0 pad
    const bool fixhi = (blockIdx.x == gridDim.x - 1) && (t == 255); // l==LLEN-1 pad
    float* outp = out + (size_t)b * COUT * LLEN + lbase + 4 * t;

    #pragma unroll 2
    for (int co = 0; co < COUT; ++co) {
        const unsigned long long p0 = wl[co * 6 + 0], n0 = wl[co * 6 + 1];
        const unsigned long long p1 = wl[co * 6 + 2], n1 = wl[co * 6 + 3];
        const unsigned long long p2 = wl[co * 6 + 4], n2 = wl[co * 6 + 5];
        const float A = eA[co], S = eS[co], Bv = eB[co], G = eG[co], Z = eZ[co];
        f32x4 r;
        {
            int pc = __popcll((xq0 ^ p0) & n0) + __popcll((xq1 ^ p1) & n1)
                   + __popcll((xq2 ^ p2) & n2);
            r.x = rprelu(fmaf(S, (float)pc, A), Bv, G, Z);
        }
        {
            int pc = __popcll((xq1 ^ p0) & n0) + __popcll((xq2 ^ p1) & n1)
                   + __popcll((xq3 ^ p2) & n2);
            r.y = rprelu(fmaf(S, (float)pc, A), Bv, G, Z);
        }
        {
            int pc = __popcll((xq2 ^ p0) & n0) + __popcll((xq3 ^ p1) & n1)
                   + __popcll((xq4 ^ p2) & n2);
            r.z = rprelu(fmaf(S, (float)pc, A), Bv, G, Z);
        }
        {
            int pc = __popcll((xq3 ^ p0) & n0) + __popcll((xq4 ^ p1) & n1)
                   + __popcll((xq5 ^ p2) & n2);
            r.w = rprelu(fmaf(S, (float)pc, A), Bv, G, Z);
        }
        if (fixlo) {   // l=0: k=0 term is zero padding
            int pc = __popcll((xq1 ^ p1) & n1) + __popcll((xq2 ^ p2) & n2);
            r.x = rprelu(fmaf(S, (float)pc + h0[co], A), Bv, G, Z);
        }
        if (fixhi) {   // l=LLEN-1: k=2 term is zero padding
            int pc = __popcll((xq3 ^ p0) & n0) + __popcll((xq4 ^ p1) & n1);
            r.w = rprelu(fmaf(S, (float)pc + h2[co], A), Bv, G, Z);
        }
        __builtin_nontemporal_store(r, (f32x4*)(outp + (size_t)co * LLEN));
    }
}

extern "C" void kernel_launch(void* const* d_in, const int* in_sizes, int n_in,
                              void* d_out, int out_size, void* d_ws, size_t ws_size,
                              hipStream_t stream) {
    const float* x      = (const float*)d_in[0];
    const float* alpha  = (const float*)d_in[1];
    const float* w      = (const float*)d_in[2];
    const float* wscale = (const float*)d_in[3];
    const float* bias   = (const float*)d_in[4];
    const float* beta   = (const float*)d_in[5];
    const float* gamma  = (const float*)d_in[6];
    const float* zeta   = (const float*)d_in[7];
    float* out = (float*)d_out;

    unsigned long long* wbits = (unsigned long long*)d_ws;
    float* epi = (float*)((char*)d_ws + 3072);
    int* nnz   = (int*)((char*)d_ws + 3072 + 512);

    pack_weights<<<1, 64, 0, stream>>>(w, wscale, bias, wbits, epi, nnz);

    dim3 grid(LLEN / LTILE, 16);
    bconv_kernel<<<grid, 256, 0, stream>>>(x, alpha, wbits, epi, nnz,
                                           beta, gamma, zeta, out);
}